// Round 5
// baseline (409.023 us; speedup 1.0000x reference)
//
#include <hip/hip_runtime.h>
#include <stdint.h>
#include <math.h>

// ---------------------------------------------------------------------------
// Generator_44555990728950. B=4096 molecules, N=32 nodes (chain), H=128,
// 16 GAT layers. All nodes of a molecule are identical up to fp rounding
// (h0 broadcast; attention weights exactly 1/2 or 1/3), so only two node
// classes exist: edge {0,31} and interior {1..30}. Deterministic pipeline in
// fp64; sampling reproduces JAX's *partitionable* threefry bit-exactly
// (jax_threefry_partitionable=True default in modern JAX):
//   split: child_i = threefry_block(key, (0, i))          [fold-like split]
//   bits : elem f  = o1 ^ o2 of threefry_block(key, (0,f)) [32-bit fold]
// Outputs fp32. 4 mols/block, 1 wave/mol, lane owns 2 columns.
// ---------------------------------------------------------------------------

struct U2 { uint32_t a, b; };

// Threefry-2x32, 20 rounds, exactly as jax._src.prng
__device__ __forceinline__ U2 threefry(uint32_t k0, uint32_t k1, uint32_t x0, uint32_t x1) {
  const uint32_t ks2 = k0 ^ k1 ^ 0x1BD11BDAu;
#define TFR(r) { x0 += x1; x1 = (x1 << (r)) | (x1 >> (32 - (r))); x1 ^= x0; }
  x0 += k0;  x1 += k1;
  TFR(13) TFR(15) TFR(26) TFR(6)
  x0 += k1;  x1 += ks2 + 1u;
  TFR(17) TFR(29) TFR(16) TFR(24)
  x0 += ks2; x1 += k0 + 2u;
  TFR(13) TFR(15) TFR(26) TFR(6)
  x0 += k0;  x1 += k1 + 3u;
  TFR(17) TFR(29) TFR(16) TFR(24)
  x0 += k1;  x1 += ks2 + 4u;
  TFR(13) TFR(15) TFR(26) TFR(6)
  x0 += ks2; x1 += k0 + 5u;
#undef TFR
  U2 r; r.a = x0; r.b = x1; return r;
}

// partitionable random_bits, 32-bit: counter = flat index (hi word 0 here)
__device__ __forceinline__ uint32_t pbits(uint32_t k0, uint32_t k1, uint32_t ctr) {
  U2 r = threefry(k0, k1, 0u, ctr);
  return r.a ^ r.b;
}

__device__ __forceinline__ float bits_to_unit(uint32_t bits) {
  return __uint_as_float((bits >> 9) | 0x3f800000u) - 1.0f;  // [0,1)
}

// f32 uniform(minval=1e-6,maxval=1-1e-6) -> gumbel, exactly jax's f32 path
__device__ __forceinline__ float jgumbel(uint32_t k0, uint32_t k1, uint32_t ctr) {
  const float minv = 1e-6f;
  const float maxv = (float)(1.0 - 1e-6);
  const float span = maxv - minv;
  float f = bits_to_unit(pbits(k0, k1, ctr));
  float u = fmaxf(minv, __fadd_rn(__fmul_rn(f, span), minv));  // no fma contraction
  return -logf(-logf(u));
}

#define NMOL 4

extern "C" __global__ void __launch_bounds__(256)
gen_kernel(const float* __restrict__ noise,
           const float* __restrict__ w1,
           const float* __restrict__ b1,
           const float* __restrict__ gat_w,
           const float* __restrict__ gat_b,
           const float* __restrict__ att_src,
           const float* __restrict__ att_dst,
           const float* __restrict__ w_atom,
           const float* __restrict__ b_atom,
           const float* __restrict__ w_hyb,
           const float* __restrict__ b_hyb,
           const float* __restrict__ w_deg,
           const float* __restrict__ b_deg,
           const float* __restrict__ w_chg,
           const float* __restrict__ b_chg,
           const float* __restrict__ w_arom,
           const float* __restrict__ b_arom,
           const float* __restrict__ w_eex,
           const float* __restrict__ b_eex,
           const float* __restrict__ w_ety,
           const float* __restrict__ b_ety,
           float* __restrict__ out)
{
  __shared__ __align__(16) float sW[4096];        // 16 KB W chunk / head weights
  __shared__ double sXe[NMOL][128];               // edge-class state
  __shared__ double sXi[NMOL][128];               // interior-class state
  __shared__ double sScr[NMOL][32];               // head logits scratch
  __shared__ double sNF[NMOL][32][18];            // node features (f64)
  __shared__ double sLP[NMOL][64];                // lp_atom[32], lp_hyb[32]

  const int t = threadIdx.x;
  const int wv = t >> 6;                 // wave = molecule slot
  const int ln = t & 63;                 // lane
  const int mol = blockIdx.x * NMOL + wv;
  const int c0 = ln << 1;                // this lane's two columns

  // ---------------- phase 0: x0 = relu(noise @ w1 + b1), identical all nodes
  {
    const float2 nz = *(const float2*)(noise + (size_t)mol * 128 + c0);
    sXe[wv][c0]     = (double)nz.x;
    sXe[wv][c0 + 1] = (double)nz.y;
  }
  {
    double h0 = 0.0, h1 = 0.0;
    for (int ch = 0; ch < 4; ++ch) {
      __syncthreads();
      const float4* src = (const float4*)(w1 + ch * 4096);
      for (int i = t; i < 1024; i += 256) ((float4*)sW)[i] = src[i];
      __syncthreads();
      #pragma unroll 8
      for (int kk = 0; kk < 32; ++kk) {
        const int k = ch * 32 + kk;
        const float2 w = *(const float2*)(&sW[kk * 128 + c0]);
        const double xv = sXe[wv][k];
        h0 = fma(xv, (double)w.x, h0);
        h1 = fma(xv, (double)w.y, h1);
      }
    }
    const float2 bb = *(const float2*)(b1 + c0);
    const double x0a = fmax(h0 + (double)bb.x, 0.0);
    const double x0b = fmax(h1 + (double)bb.y, 0.0);
    __syncthreads();                      // everyone done reading noise from sXe
    sXe[wv][c0] = x0a; sXe[wv][c0 + 1] = x0b;
    sXi[wv][c0] = x0a; sXi[wv][c0 + 1] = x0b;
  }

  // ---------------- 16 GAT layers on the two node classes
  for (int l = 0; l < 16; ++l) {
    double he0 = 0.0, he1 = 0.0, hi0 = 0.0, hi1 = 0.0;
    const float* Wl = gat_w + (size_t)l * 16384;
    for (int ch = 0; ch < 4; ++ch) {
      __syncthreads();
      const float4* src = (const float4*)(Wl + ch * 4096);
      for (int i = t; i < 1024; i += 256) ((float4*)sW)[i] = src[i];
      __syncthreads();
      #pragma unroll 4
      for (int kk = 0; kk < 32; ++kk) {
        const int k = ch * 32 + kk;
        const float2 w = *(const float2*)(&sW[kk * 128 + c0]);
        const double xe = sXe[wv][k];
        const double xi = sXi[wv][k];
        he0 = fma(xe, (double)w.x, he0);
        he1 = fma(xe, (double)w.y, he1);
        hi0 = fma(xi, (double)w.x, hi0);
        hi1 = fma(xi, (double)w.y, hi1);
      }
    }
    {
      const float2 bb = *(const float2*)(gat_b + l * 128 + c0);
      he0 += (double)bb.x; he1 += (double)bb.y;
      hi0 += (double)bb.x; hi1 += (double)bb.y;
    }
    // attention scalars e_src/e_dst for both classes (wave reduction)
    const float2 av = *(const float2*)(att_src + l * 128 + c0);
    const float2 dv = *(const float2*)(att_dst + l * 128 + c0);
    double es_e = fma(he1, (double)av.y, he0 * (double)av.x);
    double ed_e = fma(he1, (double)dv.y, he0 * (double)dv.x);
    double es_i = fma(hi1, (double)av.y, hi0 * (double)av.x);
    double ed_i = fma(hi1, (double)dv.y, hi0 * (double)dv.x);
    #pragma unroll
    for (int o = 1; o < 64; o <<= 1) {
      es_e += __shfl_xor(es_e, o, 64);
      ed_e += __shfl_xor(ed_e, o, 64);
      es_i += __shfl_xor(es_i, o, 64);
      ed_i += __shfl_xor(ed_i, o, 64);
    }
    // edge node (node 0): neighbors {0(edge),1(interior)}
    double s00 = ed_e + es_e; s00 = (s00 >= 0.0) ? s00 : 0.2 * s00;
    double s01 = ed_e + es_i; s01 = (s01 >= 0.0) ? s01 : 0.2 * s01;
    const double me = fmax(s00, s01);
    const double p0 = exp(s00 - me), p1 = exp(s01 - me);
    const double den = p0 + p1;
    const double a0 = p0 / den, a1 = p1 / den;
    const double oe0 = a0 * he0 + a1 * hi0;
    const double oe1 = a0 * he1 + a1 * hi1;
    // interior node: three equal scores -> alpha = 1/3 each
    const double ai = 1.0 / 3.0;
    const double t0 = ai * hi0, t1 = ai * hi1;
    const double oi0 = (t0 + t0) + t0;
    const double oi1 = (t1 + t1) + t1;
    // residual + relu, write back (wave-local)
    const double xe0 = fmax(sXe[wv][c0] + oe0, 0.0);
    const double xe1 = fmax(sXe[wv][c0 + 1] + oe1, 0.0);
    const double xi0 = fmax(sXi[wv][c0] + oi0, 0.0);
    const double xi1 = fmax(sXi[wv][c0 + 1] + oi1, 0.0);
    sXe[wv][c0] = xe0; sXe[wv][c0 + 1] = xe1;
    sXi[wv][c0] = xi0; sXi[wv][c0 + 1] = xi1;
  }

  // ---------------- stage head weights into sW (fp32)
  // layout: WA 0(1280) WH 1280(384) WD 1664 WC 1792 WR 1920 WEX 2048(34)
  //         WTY 2082(136) BA 2218(10) BH 2228(3) BD 2231 BC 2232 BR 2233
  //         BEX 2234 BTY 2235(4)
  __syncthreads();
  for (int i = t; i < 1280; i += 256) sW[i] = w_atom[i];
  for (int i = t; i < 384;  i += 256) sW[1280 + i] = w_hyb[i];
  if (t < 128) { sW[1664 + t] = w_deg[t]; sW[1792 + t] = w_chg[t]; sW[1920 + t] = w_arom[t]; }
  if (t < 34)  sW[2048 + t] = w_eex[t];
  if (t < 136) sW[2082 + t] = w_ety[t];
  if (t < 10)  sW[2218 + t] = b_atom[t];
  if (t < 3)   sW[2228 + t] = b_hyb[t];
  if (t == 0) { sW[2231] = b_deg[0]; sW[2232] = b_chg[0]; sW[2233] = b_arom[0]; sW[2234] = b_eex[0]; }
  if (t < 4)   sW[2235 + t] = b_ety[t];
  __syncthreads();

  // ---------------- phase A: head logits per class (lanes 0..15)
  if (ln < 10) {
    double ae = 0.0, aiv = 0.0;
    for (int c = 0; c < 128; ++c) {
      const double wv_ = (double)sW[c * 10 + ln];
      ae  = fma(sXe[wv][c], wv_, ae);
      aiv = fma(sXi[wv][c], wv_, aiv);
    }
    const double ba = (double)sW[2218 + ln];
    sScr[wv][ln]      = ae + ba;
    sScr[wv][10 + ln] = aiv + ba;
  } else if (ln < 13) {
    const int j = ln - 10;
    double ae = 0.0, aiv = 0.0;
    for (int c = 0; c < 128; ++c) {
      const double wv_ = (double)sW[1280 + c * 3 + j];
      ae  = fma(sXe[wv][c], wv_, ae);
      aiv = fma(sXi[wv][c], wv_, aiv);
    }
    const double bh = (double)sW[2228 + j];
    sScr[wv][20 + j] = ae + bh;
    sScr[wv][23 + j] = aiv + bh;
  } else if (ln < 16) {
    const int which = ln - 13;             // 0=deg 1=chg 2=arom
    const int base = 1664 + which * 128;
    double ae = 0.0, aiv = 0.0;
    for (int c = 0; c < 128; ++c) {
      const double wv_ = (double)sW[base + c];
      ae  = fma(sXe[wv][c], wv_, ae);
      aiv = fma(sXi[wv][c], wv_, aiv);
    }
    const double bz = (double)sW[2231 + which];
    sScr[wv][26 + which] = ae + bz;
    sScr[wv][29 + which] = aiv + bz;
  }
  __syncthreads();

  // ---------------- partitionable (fold-like) split(key(42), 4):
  // child_i = threefry_block((0,42), (0, i))
  const U2 k0p = threefry(0u, 42u, 0u, 0u);   // sk[0]
  const U2 k1p = threefry(0u, 42u, 0u, 1u);   // sk[1]
  const U2 k2p = threefry(0u, 42u, 0u, 2u);   // sk[2]
  const U2 k3p = threefry(0u, 42u, 0u, 3u);   // sk[3]

  // ---------------- phase B: per-node sampling + node features (lanes 0..31)
  if (ln < 32) {
    const int n = ln;
    const int lb = (n == 0 || n == 31) ? 0 : 10;    // atom logit base
    const int hb = (n == 0 || n == 31) ? 20 : 23;   // hyb logit base
    const int zb = (n == 0 || n == 31) ? 26 : 29;   // deg/chg/arom base

    // atom head
    double m = sScr[wv][lb];
    #pragma unroll
    for (int a = 1; a < 10; ++a) m = fmax(m, sScr[wv][lb + a]);
    double lsum = 0.0;
    #pragma unroll
    for (int a = 0; a < 10; ++a) lsum += exp(sScr[wv][lb + a] - m);
    const double lse = log(lsum);
    const uint32_t abase = ((uint32_t)mol * 32u + (uint32_t)n) * 10u;
    int asel = 0; double abest = 0.0;
    #pragma unroll
    for (int a = 0; a < 10; ++a) {
      const double g = (double)jgumbel(k0p.a, k0p.b, abase + (uint32_t)a);
      const double sc = sScr[wv][lb + a] + g;
      if (a == 0 || sc > abest) { abest = sc; asel = a; }
    }
    sLP[wv][n] = (sScr[wv][lb + asel] - m) - lse;

    // hyb head
    double m2 = fmax(fmax(sScr[wv][hb], sScr[wv][hb + 1]), sScr[wv][hb + 2]);
    double ls2 = exp(sScr[wv][hb] - m2) + exp(sScr[wv][hb + 1] - m2) + exp(sScr[wv][hb + 2] - m2);
    const double lse2 = log(ls2);
    const uint32_t hbase = ((uint32_t)mol * 32u + (uint32_t)n) * 3u;
    int hsel = 0; double hbest = 0.0;
    #pragma unroll
    for (int j = 0; j < 3; ++j) {
      const double g = (double)jgumbel(k1p.a, k1p.b, hbase + (uint32_t)j);
      const double sc = sScr[wv][hb + j] + g;
      if (j == 0 || sc > hbest) { hbest = sc; hsel = j; }
    }
    sLP[wv][32 + n] = (sScr[wv][hb + hsel] - m2) - lse2;

    // deg / chg / arom
    const double deg = 1.0 / (1.0 + exp(-sScr[wv][zb]));
    const double chg = tanh(sScr[wv][zb + 1]);
    const double pr  = 1.0 / (1.0 + exp(-sScr[wv][zb + 2]));
    const uint32_t ridx = (uint32_t)mol * 32u + (uint32_t)n;
    const double uu = (double)bits_to_unit(pbits(k2p.a, k2p.b, ridx));  // uniform [0,1)
    const double arom = (uu < pr) ? 1.0 : 0.0;
    const double valt[10] = {4.0/5.0, 3.0/5.0, 2.0/5.0, 1.0/5.0, 4.0/5.0,
                             2.0/5.0, 6.0/5.0, 1.0/5.0, 4.0/5.0, 4.0/5.0};
    double nf[17];
    #pragma unroll
    for (int i = 0; i < 10; ++i) nf[i] = (i == asel) ? 1.0 : 0.0;
    nf[10] = deg; nf[11] = chg;
    #pragma unroll
    for (int j = 0; j < 3; ++j) nf[12 + j] = (j == hsel) ? 1.0 : 0.0;
    nf[15] = arom; nf[16] = valt[asel];

    const size_t o = ((size_t)mol * 32 + n) * 17;
    #pragma unroll
    for (int i = 0; i < 17; ++i) { sNF[wv][n][i] = nf[i]; out[o + i] = (float)nf[i]; }
  }
  __syncthreads();

  // ---------------- phase C: lp means + edge heads
  if (ln == 62) {
    double sa = 0.0;
    for (int n = 0; n < 32; ++n) sa += sLP[wv][n];
    out[2228224 + (size_t)mol] = (float)(sa / 32.0);
  } else if (ln == 63) {
    double sh = 0.0;
    for (int n = 0; n < 32; ++n) sh += sLP[wv][32 + n];
    out[2232320 + (size_t)mol] = (float)(sh / 32.0);
  } else {
    const int e = ln;                        // 0..61
    const int nu_ = (e < 31) ? e : (e - 30);
    const int nv_ = (e < 31) ? (e + 1) : (e - 31);
    double lex = 0.0;
    double lt[4] = {0.0, 0.0, 0.0, 0.0};
    for (int i = 0; i < 17; ++i) {
      const double f = sNF[wv][nu_][i];
      lex = fma(f, (double)sW[2048 + i], lex);
      #pragma unroll
      for (int c = 0; c < 4; ++c) lt[c] = fma(f, (double)sW[2082 + i * 4 + c], lt[c]);
    }
    for (int i = 0; i < 17; ++i) {
      const double f = sNF[wv][nv_][i];
      lex = fma(f, (double)sW[2048 + 17 + i], lex);
      #pragma unroll
      for (int c = 0; c < 4; ++c) lt[c] = fma(f, (double)sW[2082 + (17 + i) * 4 + c], lt[c]);
    }
    lex += (double)sW[2234];
    #pragma unroll
    for (int c = 0; c < 4; ++c) lt[c] += (double)sW[2235 + c];

    const double pex = 1.0 / (1.0 + exp(-lex));
    out[3252224 + (size_t)mol * 62 + e] = (pex > 0.5) ? 1.f : 0.f;

    const uint32_t tbase = ((uint32_t)mol * 62u + (uint32_t)e) * 4u;
    int tsel = 0; double tbest = 0.0;
    #pragma unroll
    for (int c = 0; c < 4; ++c) {
      const double g = (double)jgumbel(k3p.a, k3p.b, tbase + (uint32_t)c);
      const double sc = lt[c] + g;
      if (c == 0 || sc > tbest) { tbest = sc; tsel = c; }
    }
    const size_t o = 2236416 + ((size_t)mol * 62 + e) * 4;
    #pragma unroll
    for (int c = 0; c < 4; ++c) out[o + c] = (c == tsel) ? 1.f : 0.f;
  }
}

extern "C" void kernel_launch(void* const* d_in, const int* in_sizes, int n_in,
                              void* d_out, int out_size, void* d_ws, size_t ws_size,
                              hipStream_t stream) {
  (void)in_sizes; (void)n_in; (void)out_size; (void)d_ws; (void)ws_size;
  hipLaunchKernelGGL(gen_kernel, dim3(1024), dim3(256), 0, stream,
                     (const float*)d_in[0],  (const float*)d_in[1],
                     (const float*)d_in[2],  (const float*)d_in[3],
                     (const float*)d_in[4],  (const float*)d_in[5],
                     (const float*)d_in[6],  (const float*)d_in[7],
                     (const float*)d_in[8],  (const float*)d_in[9],
                     (const float*)d_in[10], (const float*)d_in[11],
                     (const float*)d_in[12], (const float*)d_in[13],
                     (const float*)d_in[14], (const float*)d_in[15],
                     (const float*)d_in[16], (const float*)d_in[17],
                     (const float*)d_in[18], (const float*)d_in[19],
                     (const float*)d_in[20], (float*)d_out);
}

// Round 6
// 348.922 us; speedup vs baseline: 1.1722x; 1.1722x over previous
//
#include <hip/hip_runtime.h>
#include <stdint.h>
#include <math.h>

// ---------------------------------------------------------------------------
// Generator_44555990728950. B=4096 molecules, N=32 nodes (chain), H=128,
// 16 GAT layers. Two node classes per molecule (edge {0,31}, interior
// {1..30}); deterministic pipeline fp64; JAX partitionable threefry
// reproduced bit-exactly; outputs fp32.
// R6 restructure: barrier-free streaming. W read directly from global
// (L2-resident, coalesced float2/lane), x in wave-private LDS (interleaved
// {xe0,xi0,xe1,xi1} per k -> ds_read_b128 broadcasts), 2 molecules per wave,
// 4 waves per block, no block barriers in the main loop (wave lockstep).
// ---------------------------------------------------------------------------

struct U2 { uint32_t a, b; };

// Threefry-2x32, 20 rounds, exactly as jax._src.prng
__device__ __forceinline__ U2 threefry(uint32_t k0, uint32_t k1, uint32_t x0, uint32_t x1) {
  const uint32_t ks2 = k0 ^ k1 ^ 0x1BD11BDAu;
#define TFR(r) { x0 += x1; x1 = (x1 << (r)) | (x1 >> (32 - (r))); x1 ^= x0; }
  x0 += k0;  x1 += k1;
  TFR(13) TFR(15) TFR(26) TFR(6)
  x0 += k1;  x1 += ks2 + 1u;
  TFR(17) TFR(29) TFR(16) TFR(24)
  x0 += ks2; x1 += k0 + 2u;
  TFR(13) TFR(15) TFR(26) TFR(6)
  x0 += k0;  x1 += k1 + 3u;
  TFR(17) TFR(29) TFR(16) TFR(24)
  x0 += k1;  x1 += ks2 + 4u;
  TFR(13) TFR(15) TFR(26) TFR(6)
  x0 += ks2; x1 += k0 + 5u;
#undef TFR
  U2 r; r.a = x0; r.b = x1; return r;
}

// partitionable random_bits, 32-bit: counter = flat index; fold o1^o2
__device__ __forceinline__ uint32_t pbits(uint32_t k0, uint32_t k1, uint32_t ctr) {
  U2 r = threefry(k0, k1, 0u, ctr);
  return r.a ^ r.b;
}

__device__ __forceinline__ float bits_to_unit(uint32_t bits) {
  return __uint_as_float((bits >> 9) | 0x3f800000u) - 1.0f;  // [0,1)
}

// f32 uniform(1e-6, 1-1e-6) -> gumbel, exactly jax's f32 path
__device__ __forceinline__ float jgumbel(uint32_t k0, uint32_t k1, uint32_t ctr) {
  const float minv = 1e-6f;
  const float maxv = (float)(1.0 - 1e-6);
  const float span = maxv - minv;
  float f = bits_to_unit(pbits(k0, k1, ctr));
  float u = fmaxf(minv, __fadd_rn(__fmul_rn(f, span), minv));
  return -logf(-logf(u));
}

#define NW 4   // waves per block; 2 molecules per wave

extern "C" __global__ void __launch_bounds__(256)
gen_kernel(const float* __restrict__ noise,
           const float* __restrict__ w1,
           const float* __restrict__ b1,
           const float* __restrict__ gat_w,
           const float* __restrict__ gat_b,
           const float* __restrict__ att_src,
           const float* __restrict__ att_dst,
           const float* __restrict__ w_atom,
           const float* __restrict__ b_atom,
           const float* __restrict__ w_hyb,
           const float* __restrict__ b_hyb,
           const float* __restrict__ w_deg,
           const float* __restrict__ b_deg,
           const float* __restrict__ w_chg,
           const float* __restrict__ b_chg,
           const float* __restrict__ w_arom,
           const float* __restrict__ b_arom,
           const float* __restrict__ w_eex,
           const float* __restrict__ b_eex,
           const float* __restrict__ w_ety,
           const float* __restrict__ b_ety,
           float* __restrict__ out)
{
  // x state: per wave, per k: {xe_m0, xi_m0, xe_m1, xi_m1}
  __shared__ __align__(16) double sX[NW][128][4];      // 16 KB
  __shared__ double sScr[NW][2][32];                    // head logits, 2 KB
  __shared__ float  sNF[NW][2][32][17];                 // node features, 17 KB
  __shared__ double sLP[NW][2][64];                     // lp scratch, 4 KB

  const int t  = threadIdx.x;
  const int wv = t >> 6;
  const int ln = t & 63;
  const int molPair = (blockIdx.x * NW + wv) * 2;
  const int c0 = ln << 1;                               // lane's two columns

  // ---------------- phase 0: x0 = relu(noise @ w1 + b1) for both molecules
  {
    const float2 nz0 = *(const float2*)(noise + (size_t)molPair * 128 + c0);
    const float2 nz1 = *(const float2*)(noise + (size_t)(molPair + 1) * 128 + c0);
    sX[wv][c0][0]     = (double)nz0.x;
    sX[wv][c0 + 1][0] = (double)nz0.y;
    sX[wv][c0][1]     = (double)nz1.x;
    sX[wv][c0 + 1][1] = (double)nz1.y;
    double h00 = 0.0, h01 = 0.0, h10 = 0.0, h11 = 0.0;
    #pragma unroll 4
    for (int k = 0; k < 128; ++k) {
      const double2 nn = *(const double2*)&sX[wv][k][0];       // n_m0, n_m1
      const float2  w  = *(const float2*)(w1 + k * 128 + c0);
      const double wx = (double)w.x, wy = (double)w.y;
      h00 = fma(nn.x, wx, h00); h01 = fma(nn.x, wy, h01);
      h10 = fma(nn.y, wx, h10); h11 = fma(nn.y, wy, h11);
    }
    const float2 bb = *(const float2*)(b1 + c0);
    const double x00 = fmax(h00 + (double)bb.x, 0.0);
    const double x01 = fmax(h01 + (double)bb.y, 0.0);
    const double x10 = fmax(h10 + (double)bb.x, 0.0);
    const double x11 = fmax(h11 + (double)bb.y, 0.0);
    // lockstep: all lanes finished the read loop before any write executes
    double2 w0a = {x00, x00}, w0b = {x10, x10};
    double2 w1a = {x01, x01}, w1b = {x11, x11};
    *(double2*)&sX[wv][c0][0]     = w0a;  *(double2*)&sX[wv][c0][2]     = w0b;
    *(double2*)&sX[wv][c0 + 1][0] = w1a;  *(double2*)&sX[wv][c0 + 1][2] = w1b;
  }

  // ---------------- 16 GAT layers, W streamed from global, no staging
  for (int l = 0; l < 16; ++l) {
    __syncthreads();   // cosmetic: keeps the 4 waves in phase for L1 W reuse
    const float* __restrict__ Wl = gat_w + (size_t)l * 16384;
    double aE0x = 0.0, aE0y = 0.0, aI0x = 0.0, aI0y = 0.0;
    double aE1x = 0.0, aE1y = 0.0, aI1x = 0.0, aI1y = 0.0;
    #pragma unroll 4
    for (int k = 0; k < 128; ++k) {
      const double2 P = *(const double2*)&sX[wv][k][0];   // xe0, xi0
      const double2 Q = *(const double2*)&sX[wv][k][2];   // xe1, xi1
      const float2  w = *(const float2*)(Wl + k * 128 + c0);
      const double wx = (double)w.x, wy = (double)w.y;
      aE0x = fma(P.x, wx, aE0x); aE0y = fma(P.x, wy, aE0y);
      aI0x = fma(P.y, wx, aI0x); aI0y = fma(P.y, wy, aI0y);
      aE1x = fma(Q.x, wx, aE1x); aE1y = fma(Q.x, wy, aE1y);
      aI1x = fma(Q.y, wx, aI1x); aI1y = fma(Q.y, wy, aI1y);
    }
    {
      const float2 bb = *(const float2*)(gat_b + l * 128 + c0);
      const double bx = (double)bb.x, by = (double)bb.y;
      aE0x += bx; aE0y += by; aI0x += bx; aI0y += by;
      aE1x += bx; aE1y += by; aI1x += bx; aI1y += by;
    }
    // attention scalars (per class, per mol) via wave butterfly
    const float2 av = *(const float2*)(att_src + l * 128 + c0);
    const float2 dv = *(const float2*)(att_dst + l * 128 + c0);
    const double ax = (double)av.x, ay = (double)av.y;
    const double dx = (double)dv.x, dy = (double)dv.y;
    double esE0 = fma(aE0y, ay, aE0x * ax), edE0 = fma(aE0y, dy, aE0x * dx);
    double esI0 = fma(aI0y, ay, aI0x * ax), edI0 = fma(aI0y, dy, aI0x * dx);
    double esE1 = fma(aE1y, ay, aE1x * ax), edE1 = fma(aE1y, dy, aE1x * dx);
    double esI1 = fma(aI1y, ay, aI1x * ax), edI1 = fma(aI1y, dy, aI1x * dx);
    #pragma unroll
    for (int o = 1; o < 64; o <<= 1) {
      esE0 += __shfl_xor(esE0, o, 64); edE0 += __shfl_xor(edE0, o, 64);
      esI0 += __shfl_xor(esI0, o, 64); edI0 += __shfl_xor(edI0, o, 64);
      esE1 += __shfl_xor(esE1, o, 64); edE1 += __shfl_xor(edE1, o, 64);
      esI1 += __shfl_xor(esI1, o, 64); edI1 += __shfl_xor(edI1, o, 64);
    }
    // residual state (lane-local slots)
    const double2 r0a = *(const double2*)&sX[wv][c0][0];
    const double2 r0b = *(const double2*)&sX[wv][c0][2];
    const double2 r1a = *(const double2*)&sX[wv][c0 + 1][0];
    const double2 r1b = *(const double2*)&sX[wv][c0 + 1][2];

    // mol 0
    double s00 = edE0 + esE0; s00 = (s00 >= 0.0) ? s00 : 0.2 * s00;
    double s01 = edE0 + esI0; s01 = (s01 >= 0.0) ? s01 : 0.2 * s01;
    double me  = fmax(s00, s01);
    double p0  = exp(s00 - me), p1 = exp(s01 - me);
    double den = p0 + p1;
    double A0 = p0 / den, A1 = p1 / den;
    const double oE0x = A0 * aE0x + A1 * aI0x;
    const double oE0y = A0 * aE0y + A1 * aI0y;
    const double tI0x = (1.0 / 3.0) * aI0x, tI0y = (1.0 / 3.0) * aI0y;
    const double oI0x = (tI0x + tI0x) + tI0x;
    const double oI0y = (tI0y + tI0y) + tI0y;
    // mol 1
    double s10 = edE1 + esE1; s10 = (s10 >= 0.0) ? s10 : 0.2 * s10;
    double s11 = edE1 + esI1; s11 = (s11 >= 0.0) ? s11 : 0.2 * s11;
    double me1 = fmax(s10, s11);
    double q0  = exp(s10 - me1), q1 = exp(s11 - me1);
    double den1 = q0 + q1;
    double B0 = q0 / den1, B1 = q1 / den1;
    const double oE1x = B0 * aE1x + B1 * aI1x;
    const double oE1y = B0 * aE1y + B1 * aI1y;
    const double tI1x = (1.0 / 3.0) * aI1x, tI1y = (1.0 / 3.0) * aI1y;
    const double oI1x = (tI1x + tI1x) + tI1x;
    const double oI1y = (tI1y + tI1y) + tI1y;

    double2 n0a, n0b, n1a, n1b;
    n0a.x = fmax(r0a.x + oE0x, 0.0);  n0a.y = fmax(r0a.y + oI0x, 0.0);
    n0b.x = fmax(r0b.x + oE1x, 0.0);  n0b.y = fmax(r0b.y + oI1x, 0.0);
    n1a.x = fmax(r1a.x + oE0y, 0.0);  n1a.y = fmax(r1a.y + oI0y, 0.0);
    n1b.x = fmax(r1b.x + oE1y, 0.0);  n1b.y = fmax(r1b.y + oI1y, 0.0);
    *(double2*)&sX[wv][c0][0]     = n0a;  *(double2*)&sX[wv][c0][2]     = n0b;
    *(double2*)&sX[wv][c0 + 1][0] = n1a;  *(double2*)&sX[wv][c0 + 1][2] = n1b;
  }

  // ---------------- phase A: head logits per class (lanes 0..31; 16 per mol)
  {
    const int mh   = ln >> 4;          // mol half for lanes < 32
    const int lidx = ln & 15;
    if (ln < 32) {
      double ae = 0.0, aiv = 0.0;
      if (lidx < 10) {
        for (int c = 0; c < 128; ++c) {
          const double2 X = *(const double2*)&sX[wv][c][2 * mh];
          const double wv_ = (double)w_atom[c * 10 + lidx];
          ae  = fma(X.x, wv_, ae);
          aiv = fma(X.y, wv_, aiv);
        }
        const double ba = (double)b_atom[lidx];
        sScr[wv][mh][lidx]      = ae + ba;
        sScr[wv][mh][10 + lidx] = aiv + ba;
      } else if (lidx < 13) {
        const int j = lidx - 10;
        for (int c = 0; c < 128; ++c) {
          const double2 X = *(const double2*)&sX[wv][c][2 * mh];
          const double wv_ = (double)w_hyb[c * 3 + j];
          ae  = fma(X.x, wv_, ae);
          aiv = fma(X.y, wv_, aiv);
        }
        const double bh = (double)b_hyb[j];
        sScr[wv][mh][20 + j] = ae + bh;
        sScr[wv][mh][23 + j] = aiv + bh;
      } else {
        const int which = lidx - 13;   // 0=deg 1=chg 2=arom
        const float* wp = (which == 0) ? w_deg : (which == 1) ? w_chg : w_arom;
        for (int c = 0; c < 128; ++c) {
          const double2 X = *(const double2*)&sX[wv][c][2 * mh];
          const double wv_ = (double)wp[c];
          ae  = fma(X.x, wv_, ae);
          aiv = fma(X.y, wv_, aiv);
        }
        const double bz = (double)((which == 0) ? b_deg[0] : (which == 1) ? b_chg[0] : b_arom[0]);
        sScr[wv][mh][26 + which] = ae + bz;
        sScr[wv][mh][29 + which] = aiv + bz;
      }
    }
  }

  // partitionable split(key(42),4): child_i = threefry((0,42),(0,i))
  const U2 k0p = threefry(0u, 42u, 0u, 0u);
  const U2 k1p = threefry(0u, 42u, 0u, 1u);
  const U2 k2p = threefry(0u, 42u, 0u, 2u);
  const U2 k3p = threefry(0u, 42u, 0u, 3u);

  // ---------------- phase B: per-node sampling, all 64 lanes (32 nodes x 2 mols)
  {
    const int mh  = ln >> 5;
    const int n   = ln & 31;
    const int mol = molPair + mh;
    const int lb = (n == 0 || n == 31) ? 0 : 10;
    const int hb = (n == 0 || n == 31) ? 20 : 23;
    const int zb = (n == 0 || n == 31) ? 26 : 29;
    const double* scr = sScr[wv][mh];

    double m = scr[lb];
    #pragma unroll
    for (int a = 1; a < 10; ++a) m = fmax(m, scr[lb + a]);
    double lsum = 0.0;
    #pragma unroll
    for (int a = 0; a < 10; ++a) lsum += exp(scr[lb + a] - m);
    const double lse = log(lsum);
    const uint32_t abase = ((uint32_t)mol * 32u + (uint32_t)n) * 10u;
    int asel = 0; double abest = 0.0;
    #pragma unroll
    for (int a = 0; a < 10; ++a) {
      const double g = (double)jgumbel(k0p.a, k0p.b, abase + (uint32_t)a);
      const double sc = scr[lb + a] + g;
      if (a == 0 || sc > abest) { abest = sc; asel = a; }
    }
    sLP[wv][mh][n] = (scr[lb + asel] - m) - lse;

    double m2 = fmax(fmax(scr[hb], scr[hb + 1]), scr[hb + 2]);
    double ls2 = exp(scr[hb] - m2) + exp(scr[hb + 1] - m2) + exp(scr[hb + 2] - m2);
    const double lse2 = log(ls2);
    const uint32_t hbase = ((uint32_t)mol * 32u + (uint32_t)n) * 3u;
    int hsel = 0; double hbest = 0.0;
    #pragma unroll
    for (int j = 0; j < 3; ++j) {
      const double g = (double)jgumbel(k1p.a, k1p.b, hbase + (uint32_t)j);
      const double sc = scr[hb + j] + g;
      if (j == 0 || sc > hbest) { hbest = sc; hsel = j; }
    }
    sLP[wv][mh][32 + n] = (scr[hb + hsel] - m2) - lse2;

    const double deg = 1.0 / (1.0 + exp(-scr[zb]));
    const double chg = tanh(scr[zb + 1]);
    const double pr  = 1.0 / (1.0 + exp(-scr[zb + 2]));
    const uint32_t ridx = (uint32_t)mol * 32u + (uint32_t)n;
    const double uu = (double)bits_to_unit(pbits(k2p.a, k2p.b, ridx));
    const double arom = (uu < pr) ? 1.0 : 0.0;
    const double valt[10] = {4.0/5.0, 3.0/5.0, 2.0/5.0, 1.0/5.0, 4.0/5.0,
                             2.0/5.0, 6.0/5.0, 1.0/5.0, 4.0/5.0, 4.0/5.0};
    double nf[17];
    #pragma unroll
    for (int i = 0; i < 10; ++i) nf[i] = (i == asel) ? 1.0 : 0.0;
    nf[10] = deg; nf[11] = chg;
    #pragma unroll
    for (int j = 0; j < 3; ++j) nf[12 + j] = (j == hsel) ? 1.0 : 0.0;
    nf[15] = arom; nf[16] = valt[asel];

    const size_t o = ((size_t)mol * 32 + n) * 17;
    #pragma unroll
    for (int i = 0; i < 17; ++i) {
      sNF[wv][mh][n][i] = (float)nf[i];
      out[o + i] = (float)nf[i];
    }
  }

  // ---------------- phase C: lp means + edge heads (2 mols sequentially)
  #pragma unroll
  for (int m = 0; m < 2; ++m) {
    const int mol = molPair + m;
    if (ln == 62) {
      double sa = 0.0;
      for (int n = 0; n < 32; ++n) sa += sLP[wv][m][n];
      out[2228224 + (size_t)mol] = (float)(sa / 32.0);
    } else if (ln == 63) {
      double sh = 0.0;
      for (int n = 0; n < 32; ++n) sh += sLP[wv][m][32 + n];
      out[2232320 + (size_t)mol] = (float)(sh / 32.0);
    } else {
      const int e = ln;                       // 0..61
      const int nu_ = (e < 31) ? e : (e - 30);
      const int nv_ = (e < 31) ? (e + 1) : (e - 31);
      double lex = 0.0;
      double lt[4] = {0.0, 0.0, 0.0, 0.0};
      for (int i = 0; i < 17; ++i) {
        const double f = (double)sNF[wv][m][nu_][i];
        lex = fma(f, (double)w_eex[i], lex);
        #pragma unroll
        for (int c = 0; c < 4; ++c) lt[c] = fma(f, (double)w_ety[i * 4 + c], lt[c]);
      }
      for (int i = 0; i < 17; ++i) {
        const double f = (double)sNF[wv][m][nv_][i];
        lex = fma(f, (double)w_eex[17 + i], lex);
        #pragma unroll
        for (int c = 0; c < 4; ++c) lt[c] = fma(f, (double)w_ety[(17 + i) * 4 + c], lt[c]);
      }
      lex += (double)b_eex[0];
      #pragma unroll
      for (int c = 0; c < 4; ++c) lt[c] += (double)b_ety[c];

      const double pex = 1.0 / (1.0 + exp(-lex));
      out[3252224 + (size_t)mol * 62 + e] = (pex > 0.5) ? 1.f : 0.f;

      const uint32_t tbase = ((uint32_t)mol * 62u + (uint32_t)e) * 4u;
      int tsel = 0; double tbest = 0.0;
      #pragma unroll
      for (int c = 0; c < 4; ++c) {
        const double g = (double)jgumbel(k3p.a, k3p.b, tbase + (uint32_t)c);
        const double sc = lt[c] + g;
        if (c == 0 || sc > tbest) { tbest = sc; tsel = c; }
      }
      const size_t o = 2236416 + ((size_t)mol * 62 + e) * 4;
      #pragma unroll
      for (int c = 0; c < 4; ++c) out[o + c] = (c == tsel) ? 1.f : 0.f;
    }
  }
}

extern "C" void kernel_launch(void* const* d_in, const int* in_sizes, int n_in,
                              void* d_out, int out_size, void* d_ws, size_t ws_size,
                              hipStream_t stream) {
  (void)in_sizes; (void)n_in; (void)out_size; (void)d_ws; (void)ws_size;
  hipLaunchKernelGGL(gen_kernel, dim3(512), dim3(256), 0, stream,
                     (const float*)d_in[0],  (const float*)d_in[1],
                     (const float*)d_in[2],  (const float*)d_in[3],
                     (const float*)d_in[4],  (const float*)d_in[5],
                     (const float*)d_in[6],  (const float*)d_in[7],
                     (const float*)d_in[8],  (const float*)d_in[9],
                     (const float*)d_in[10], (const float*)d_in[11],
                     (const float*)d_in[12], (const float*)d_in[13],
                     (const float*)d_in[14], (const float*)d_in[15],
                     (const float*)d_in[16], (const float*)d_in[17],
                     (const float*)d_in[18], (const float*)d_in[19],
                     (const float*)d_in[20], (float*)d_out);
}